// Round 10
// baseline (766.509 us; speedup 1.0000x reference)
//
#include <hip/hip_runtime.h>
#include <hip/hip_bf16.h>

// Elman RNN, persistent kernel v7 — TWO independent groups per block.
// h_t = tanh([h_{t-1} | x_t] @ [Wh|Wi]^T + (Wh_b+Wi_b)); out = h_T @ Wo^T + Wo_b
// T=128, B=512, E=256, H=1024, O=256.
//
// 32 groups x 16 rows. Block(gp,co) owns cols co*64..+64 of groups gA=2gp,
// gB=2gp+1 — SAME Wh/Wi fragment registers serve both (weights shared), so the
// second stream is free in registers. Per step the two streams interleave:
// pollA/issueA hidden under xA, pollB/issueB under xB, h-MFMAs of A and B are
// independent chains. Sync+barrier+epilogue overhead amortizes over 2x work.
//
// Protocol (hard-won): asm sc0 sc1 loads/stores for all h/flag traffic
// (local-L2-served for co-located groups, r4/r5/r9: FETCH ~107MB), RELAXED
// ordering only via explicit s_waitcnt vmcnt(0), and EVERY asm-load ->
// register-consumer path fenced with sched_barrier(0) (rule #18; r6 race).
// Never compiler AGENT/SYSTEM atomics on the hot path (r7/r8: MALL storms).

#define T_ 128
#define B_ 512
#define E_ 256
#define H_ 1024
#define O_ 256
#define RG 16            // rows per group
#define HB (B_ * H_)     // elems per h slot (1 MB bf16)

typedef __bf16 bf16x8 __attribute__((ext_vector_type(8)));
typedef float  f32x2  __attribute__((ext_vector_type(2)));
typedef float  f32x4  __attribute__((ext_vector_type(4)));
typedef unsigned int u32x4 __attribute__((ext_vector_type(4)));

static __device__ __forceinline__ unsigned short f2bf(float f) {
  unsigned u = __float_as_uint(f);
  u += 0x7fff + ((u >> 16) & 1);  // RNE
  return (unsigned short)(u >> 16);
}
static __device__ __forceinline__ unsigned pk2(float a, float b) {
  return (unsigned)f2bf(a) | ((unsigned)f2bf(b) << 16);
}
static __device__ __forceinline__ bf16x8 cvt8(const float* p) {
  float4 f0 = reinterpret_cast<const float4*>(p)[0];
  float4 f1 = reinterpret_cast<const float4*>(p)[1];
  union { u32x4 u; bf16x8 v; } r;
  r.u = (u32x4){pk2(f0.x, f0.y), pk2(f0.z, f0.w), pk2(f1.x, f1.y), pk2(f1.z, f1.w)};
  return r.v;
}
// tanh(x) = 1 - 2/(exp2(2*log2e*x)+1)
static __device__ __forceinline__ float fast_tanh(float x) {
  float e = __builtin_amdgcn_exp2f(x * 2.8853900817779268f);
  return 1.f - 2.f / (e + 1.f);
}

// ---- h staging (16 rows x 1024 cols bf16 = 32KB per group) ----
static __device__ __forceinline__ void stage_issue(const unsigned char* hb, int tid,
                                                   u32x4& s0, u32x4& s1,
                                                   u32x4& s2, u32x4& s3) {
  asm volatile("global_load_dwordx4 %0, %1, off sc0 sc1"
               : "=v"(s0) : "v"(hb + (size_t)(0 * 512 + tid) * 16) : "memory");
  asm volatile("global_load_dwordx4 %0, %1, off sc0 sc1"
               : "=v"(s1) : "v"(hb + (size_t)(1 * 512 + tid) * 16) : "memory");
  asm volatile("global_load_dwordx4 %0, %1, off sc0 sc1"
               : "=v"(s2) : "v"(hb + (size_t)(2 * 512 + tid) * 16) : "memory");
  asm volatile("global_load_dwordx4 %0, %1, off sc0 sc1"
               : "=v"(s3) : "v"(hb + (size_t)(3 * 512 + tid) * 16) : "memory");
}
// write one staged tile into swizzled LDS (call AFTER the vmcnt(0)+fence)
static __device__ __forceinline__ void stage_write(int tid, unsigned char* As,
                                                   u32x4 s0, u32x4 s1,
                                                   u32x4 s2, u32x4 s3) {
#define RNN_ST(J, SV)                                                           \
  {                                                                             \
    int id = (J) * 512 + tid;                                                   \
    int row = id >> 7, c = id & 127;                                            \
    *reinterpret_cast<u32x4*>(&As[row * 2048 + ((c ^ (row & 7)) << 4)]) = SV;   \
  }
  RNN_ST(0, s0) RNN_ST(1, s1) RNN_ST(2, s2) RNN_ST(3, s3)
#undef RNN_ST
}

// Poll the 16 flag words of one group (L2-served asm loads + rule-#18 fence).
static __device__ __forceinline__ void poll16(const unsigned* fl, unsigned tgt) {
  for (;;) {
    u32x4 a, b, c, d;
    asm volatile("global_load_dwordx4 %0, %1, off sc0 sc1" : "=v"(a) : "v"(fl) : "memory");
    asm volatile("global_load_dwordx4 %0, %1, off sc0 sc1" : "=v"(b) : "v"(fl + 4) : "memory");
    asm volatile("global_load_dwordx4 %0, %1, off sc0 sc1" : "=v"(c) : "v"(fl + 8) : "memory");
    asm volatile("global_load_dwordx4 %0, %1, off sc0 sc1" : "=v"(d) : "v"(fl + 12) : "memory");
    asm volatile("s_waitcnt vmcnt(0)" ::: "memory");
    __builtin_amdgcn_sched_barrier(0);  // rule #18 fence
    unsigned m = a.x;
    m = min(m, a.y); m = min(m, a.z); m = min(m, a.w);
    m = min(m, b.x); m = min(m, b.y); m = min(m, b.z); m = min(m, b.w);
    m = min(m, c.x); m = min(m, c.y); m = min(m, c.z); m = min(m, c.w);
    m = min(m, d.x); m = min(m, d.y); m = min(m, d.z); m = min(m, d.w);
    if (m >= tgt) return;
    __builtin_amdgcn_s_sleep(1);
  }
}

// ---------------------------------------------------------------------------
__global__ void prep_kernel(const float* __restrict__ seq,
                            unsigned short* __restrict__ seq_bf,
                            unsigned* __restrict__ flags) {
  size_t idx = (size_t)blockIdx.x * blockDim.x + threadIdx.x;
  size_t stride = (size_t)gridDim.x * blockDim.x;
  const size_t nchunk = (size_t)T_ * B_ * E_ / 8;
  for (size_t i = idx; i < nchunk; i += stride) {
    union { bf16x8 v; u32x4 u; } r;
    r.v = cvt8(seq + i * 8);
    *reinterpret_cast<u32x4*>(seq_bf + i * 8) = r.u;
  }
  if (idx < 512) {
    unsigned z = 0;
    asm volatile("global_store_dword %0, %1, off sc0 sc1"
                 :: "v"(flags + idx), "v"(z) : "memory");
  }
}

// ---------------------------------------------------------------------------
__global__ __launch_bounds__(512, 2) void rnn_fused(
    const unsigned short* __restrict__ seq_bf, const float* __restrict__ Wh_w,
    const float* __restrict__ Wh_b, const float* __restrict__ Wi_w,
    const float* __restrict__ Wi_b, const float* __restrict__ Wo_w,
    const float* __restrict__ Wo_b,
    unsigned short* __restrict__ hbuf, unsigned* __restrict__ flags,
    float* __restrict__ out) {
  __shared__ __align__(16) unsigned char As[2][RG * 2048];  // 64 KB: gA, gB tiles
  __shared__ __align__(16) float red[2][2][RG][64];         // 16 KB: [grp][wk]

  const int tid = threadIdx.x;
  const int bid = blockIdx.x;
  // bid = co*16 + gp: the 16 blocks of a gp-set share bid%16 -> same bid%8 ->
  // same XCD (heuristic; sc0 sc1 keeps it correct regardless).
  const int gp = bid & 15, co = bid >> 4;   // gp 0..15, co 0..15
  const int gA = gp * 2, gB = gp * 2 + 1;
  const int RA = gA * RG, RB = gB * RG, C0 = co * 64;
  const int lane = tid & 63, wave = tid >> 6;
  const int wn = (wave & 3) * 16;  // n-offset in [0,64)
  const int wk = wave >> 2;        // k-split 0/1 (K-slice 512)
  const int l15 = lane & 15, k4 = lane >> 4;
  const int mycol = C0 + wn + l15;

  // ---- weight fragments (shared by both groups) for all 128 steps
  bf16x8 bh[16];
  {
    const float* whp = Wh_w + (size_t)mycol * H_ + wk * 512 + k4 * 8;
#pragma unroll
    for (int ks = 0; ks < 16; ++ks) bh[ks] = cvt8(whp + ks * 32);
  }
  bf16x8 wif[4];
  {
    const float* wip = Wi_w + (size_t)mycol * E_ + wk * 128 + k4 * 8;
#pragma unroll
    for (int ks = 0; ks < 4; ++ks) wif[ks] = cvt8(wip + ks * 32);
  }
  const int erow = tid >> 5, ec0 = (tid & 31) * 2;
  const float bias0 = Wh_b[C0 + ec0] + Wi_b[C0 + ec0];
  const float bias1 = Wh_b[C0 + ec0 + 1] + Wi_b[C0 + ec0 + 1];
  const unsigned* flA = flags + gA * 16;
  const unsigned* flB = flags + gB * 16;
  unsigned* myflA = flags + gA * 16 + co;
  unsigned* myflB = flags + gB * 16 + co;
  const size_t hoffA = ((size_t)(RA + erow) * H_ + C0 + ec0) * 2;  // bytes
  const size_t hoffB = ((size_t)(RB + erow) * H_ + C0 + ec0) * 2;

  for (int t = 0; t < T_; ++t) {
    f32x4 accA = {0.f, 0.f, 0.f, 0.f}, accB = {0.f, 0.f, 0.f, 0.f};
    u32x4 a0, a1, a2, a3, b0, b1, b2, b3;
    const unsigned char* hbase =
        (const unsigned char*)hbuf + (size_t)((t - 1) & 1) * (HB * 2);
    // ---- stream A: poll, issue loads; x-part hides them
    if (t > 0) {
      poll16(flA, (unsigned)t);
      stage_issue(hbase + (size_t)RA * 2048, tid, a0, a1, a2, a3);
    }
    {
      const unsigned short* xp =
          seq_bf + ((size_t)t * B_ + RA + l15) * E_ + wk * 128 + k4 * 8;
#pragma unroll
      for (int ks = 0; ks < 4; ++ks) {
        bf16x8 a = *reinterpret_cast<const bf16x8*>(xp + ks * 32);
        accA = __builtin_amdgcn_mfma_f32_16x16x32_bf16(a, wif[ks], accA, 0, 0, 0);
      }
    }
    // ---- stream B: poll (producers had slack), issue; xB hides
    if (t > 0) {
      poll16(flB, (unsigned)t);
      stage_issue(hbase + (size_t)RB * 2048, tid, b0, b1, b2, b3);
    }
    {
      const unsigned short* xp =
          seq_bf + ((size_t)t * B_ + RB + l15) * E_ + wk * 128 + k4 * 8;
#pragma unroll
      for (int ks = 0; ks < 4; ++ks) {
        bf16x8 a = *reinterpret_cast<const bf16x8*>(xp + ks * 32);
        accB = __builtin_amdgcn_mfma_f32_16x16x32_bf16(a, wif[ks], accB, 0, 0, 0);
      }
    }
    if (t > 0) {
      asm volatile("s_waitcnt vmcnt(0)" ::: "memory");
      __builtin_amdgcn_sched_barrier(0);  // rule #18 fence
      stage_write(tid, As[0], a0, a1, a2, a3);
      stage_write(tid, As[1], b0, b1, b2, b3);
    }
    __syncthreads();
    if (t > 0) {
      // ---- h-parts: two independent 16-MFMA chains (A,B interleave as ILP)
#pragma unroll
      for (int ks = 0; ks < 16; ++ks) {
        int c = wk * 64 + ks * 4 + k4;
        int off = ((c ^ (l15 & 7)) << 4) + l15 * 2048;
        bf16x8 aA = *reinterpret_cast<const bf16x8*>(&As[0][off]);
        bf16x8 aB = *reinterpret_cast<const bf16x8*>(&As[1][off]);
        accA = __builtin_amdgcn_mfma_f32_16x16x32_bf16(aA, bh[ks], accA, 0, 0, 0);
        accB = __builtin_amdgcn_mfma_f32_16x16x32_bf16(aB, bh[ks], accB, 0, 0, 0);
      }
    }
    // ---- k-split partials (C layout: col=l15, row=k4*4+r)
#pragma unroll
    for (int r = 0; r < 4; ++r) {
      red[0][wk][k4 * 4 + r][wn + l15] = accA[r];
      red[1][wk][k4 * 4 + r][wn + l15] = accB[r];
    }
    __syncthreads();
    // ---- distributed epilogue for both groups: 2 cols each -> 4B stores
    {
      unsigned char* dbase = (unsigned char*)hbuf + (size_t)(t & 1) * (HB * 2);
      f32x2 v0 = *reinterpret_cast<const f32x2*>(&red[0][0][erow][ec0]);
      f32x2 v1 = *reinterpret_cast<const f32x2*>(&red[0][1][erow][ec0]);
      unsigned pA = pk2(fast_tanh(v0[0] + v1[0] + bias0),
                        fast_tanh(v0[1] + v1[1] + bias1));
      asm volatile("global_store_dword %0, %1, off sc0 sc1"
                   :: "v"(dbase + hoffA), "v"(pA) : "memory");
      f32x2 w0 = *reinterpret_cast<const f32x2*>(&red[1][0][erow][ec0]);
      f32x2 w1 = *reinterpret_cast<const f32x2*>(&red[1][1][erow][ec0]);
      unsigned pB = pk2(fast_tanh(w0[0] + w1[0] + bias0),
                        fast_tanh(w0[1] + w1[1] + bias1));
      asm volatile("global_store_dword %0, %1, off sc0 sc1"
                   :: "v"(dbase + hoffB), "v"(pB) : "memory");
    }
    asm volatile("s_waitcnt vmcnt(0)" ::: "memory");  // h stores acked
    __syncthreads();
    if (tid == 0) {
      unsigned fv = (unsigned)(t + 1);
      asm volatile("global_store_dword %0, %1, off sc0 sc1"
                   :: "v"(myflA), "v"(fv) : "memory");
      asm volatile("global_store_dword %0, %1, off sc0 sc1"
                   :: "v"(myflB), "v"(fv) : "memory");
    }
  }

  // ---- final GEMM: out = h_T @ Wo^T + Wo_b (co<4 blocks cover 512x256)
  if (co >= 4) return;
  {
    poll16(flA, (unsigned)T_);
    poll16(flB, (unsigned)T_);
    const unsigned char* hbase =
        (const unsigned char*)hbuf + (size_t)((T_ - 1) & 1) * (HB * 2);
    u32x4 a0, a1, a2, a3, b0, b1, b2, b3;
    stage_issue(hbase + (size_t)RA * 2048, tid, a0, a1, a2, a3);
    stage_issue(hbase + (size_t)RB * 2048, tid, b0, b1, b2, b3);
    asm volatile("s_waitcnt vmcnt(0)" ::: "memory");
    __builtin_amdgcn_sched_barrier(0);
    stage_write(tid, As[0], a0, a1, a2, a3);
    stage_write(tid, As[1], b0, b1, b2, b3);
    __syncthreads();
    f32x4 accA = {0.f, 0.f, 0.f, 0.f}, accB = {0.f, 0.f, 0.f, 0.f};
    const int oc = C0 + wn + l15;  // [0,256)
    const float* wop = Wo_w + (size_t)oc * H_ + wk * 512 + k4 * 8;
#pragma unroll
    for (int ks = 0; ks < 16; ++ks) {
      int c = wk * 64 + ks * 4 + k4;
      int off = ((c ^ (l15 & 7)) << 4) + l15 * 2048;
      bf16x8 b = cvt8(wop + ks * 32);
      bf16x8 aA = *reinterpret_cast<const bf16x8*>(&As[0][off]);
      bf16x8 aB = *reinterpret_cast<const bf16x8*>(&As[1][off]);
      accA = __builtin_amdgcn_mfma_f32_16x16x32_bf16(aA, b, accA, 0, 0, 0);
      accB = __builtin_amdgcn_mfma_f32_16x16x32_bf16(aB, b, accB, 0, 0, 0);
    }
#pragma unroll
    for (int r = 0; r < 4; ++r) {
      red[0][wk][k4 * 4 + r][wn + l15] = accA[r];
      red[1][wk][k4 * 4 + r][wn + l15] = accB[r];
    }
    __syncthreads();
    {
      f32x2 ob = {Wo_b[C0 + ec0], Wo_b[C0 + ec0 + 1]};
      f32x2 v0 = *reinterpret_cast<const f32x2*>(&red[0][0][erow][ec0]);
      f32x2 v1 = *reinterpret_cast<const f32x2*>(&red[0][1][erow][ec0]);
      f32x2 oA = {v0[0] + v1[0] + ob[0], v0[1] + v1[1] + ob[1]};
      *reinterpret_cast<f32x2*>(out + (size_t)(RA + erow) * O_ + C0 + ec0) = oA;
      f32x2 w0 = *reinterpret_cast<const f32x2*>(&red[1][0][erow][ec0]);
      f32x2 w1 = *reinterpret_cast<const f32x2*>(&red[1][1][erow][ec0]);
      f32x2 oB = {w0[0] + w1[0] + ob[0], w0[1] + w1[1] + ob[1]};
      *reinterpret_cast<f32x2*>(out + (size_t)(RB + erow) * O_ + C0 + ec0) = oB;
    }
  }
}

// ---------------------------------------------------------------------------
extern "C" void kernel_launch(void* const* d_in, const int* in_sizes, int n_in,
                              void* d_out, int out_size, void* d_ws, size_t ws_size,
                              hipStream_t stream) {
  const float* seq  = (const float*)d_in[0];
  const float* Wh_w = (const float*)d_in[1];
  const float* Wh_b = (const float*)d_in[2];
  const float* Wi_w = (const float*)d_in[3];
  const float* Wi_b = (const float*)d_in[4];
  const float* Wo_w = (const float*)d_in[5];
  const float* Wo_b = (const float*)d_in[6];

  char* ws = (char*)d_ws;
  unsigned short* hbuf   = (unsigned short*)ws; ws += (size_t)2 * HB * 2;  // 2 MB
  unsigned*       flags  = (unsigned*)ws;       ws += 4096;                // 512 words
  unsigned short* seq_bf = (unsigned short*)ws;                            // 32 MB

  prep_kernel<<<2048, 256, 0, stream>>>(seq, seq_bf, flags);
  rnn_fused<<<256, 512, 0, stream>>>(seq_bf, Wh_w, Wh_b, Wi_w, Wi_b, Wo_w, Wo_b,
                                     hbuf, flags, (float*)d_out);
}